// Round 1
// baseline (1103.756 us; speedup 1.0000x reference)
//
#include <hip/hip_runtime.h>
#include <math.h>

#define H       2048
#define E       64
#define NCHUNK  16          // chunks of 128 floats (512 B) across H
#define T_TOK   32768
#define GATES_OFF   0
#define IDX_OFF     65536
#define LOSS_OFF    131072

// ---- zero the 128-float accumulator (replaces the old transpose kernel) ----
__global__ void zero_accum_kernel(float* __restrict__ accum) {
    accum[threadIdx.x] = 0.f;    // 128 threads
}

// ---------------- main gating kernel ----------------
// lane = token (64 tokens/block), acc[64] = one logit per expert in VGPRs.
// 8 waves split H: wave w owns bytes [c*512 + w*64, +64) of each token row
// -> each lane reads exactly one full 64B line per chunk (no LDS staging).
// W reads are wave-uniform -> scalar pipe (s_load), zero VALU cost.
__global__ __launch_bounds__(512) void gate_main_kernel(
        const float* __restrict__ x,         // (T, H) fp32
        const float* __restrict__ W,         // (E, H) fp32, row-major
        float* __restrict__ out,
        float* __restrict__ accum)           // [0:64) sum probs, [64:128) counts
{
    __shared__ float redf[4][64][64];        // 64 KB: K-reduction, then p/cnt staging

    const int tid   = threadIdx.x;
    const int lane  = tid & 63;
    const int wv    = tid >> 6;
    const int wvu   = __builtin_amdgcn_readfirstlane(wv);   // force SGPR-uniform
    const int token = blockIdx.x * 64 + lane;

    const float4* xrow = (const float4*)(x + (size_t)token * H) + wvu * 4;
    const float4* Wv   = (const float4*)W;   // [E][512] float4 view

    float acc[E];
#pragma unroll
    for (int e = 0; e < E; ++e) acc[e] = 0.f;

    // prefetch chunk 0 (one 64B line per lane)
    float4 xc0 = xrow[0], xc1 = xrow[1], xc2 = xrow[2], xc3 = xrow[3];

    for (int c = 0; c < NCHUNK; ++c) {
        // prefetch next chunk's line while FMAs run (last iter re-reads, L1 hit)
        const int cn = (c + 1 < NCHUNK) ? (c + 1) * 32 : c * 32;
        float4 xn0 = xrow[cn + 0];
        float4 xn1 = xrow[cn + 1];
        float4 xn2 = xrow[cn + 2];
        float4 xn3 = xrow[cn + 3];

        // uniform W base for this chunk; per-e offsets fold into s_load immediates
        const float4* wp = Wv + c * 32 + wvu * 4;
#pragma unroll
        for (int e = 0; e < E; ++e) {
            float4 w0 = wp[e * 512 + 0];
            float4 w1 = wp[e * 512 + 1];
            float4 w2 = wp[e * 512 + 2];
            float4 w3 = wp[e * 512 + 3];
            float a = acc[e];
            a = fmaf(xc0.x, w0.x, a);
            a = fmaf(xc0.y, w0.y, a);
            a = fmaf(xc0.z, w0.z, a);
            a = fmaf(xc0.w, w0.w, a);
            a = fmaf(xc1.x, w1.x, a);
            a = fmaf(xc1.y, w1.y, a);
            a = fmaf(xc1.z, w1.z, a);
            a = fmaf(xc1.w, w1.w, a);
            a = fmaf(xc2.x, w2.x, a);
            a = fmaf(xc2.y, w2.y, a);
            a = fmaf(xc2.z, w2.z, a);
            a = fmaf(xc2.w, w2.w, a);
            a = fmaf(xc3.x, w3.x, a);
            a = fmaf(xc3.y, w3.y, a);
            a = fmaf(xc3.z, w3.z, a);
            a = fmaf(xc3.w, w3.w, a);
            acc[e] = a;
        }
        xc0 = xn0; xc1 = xn1; xc2 = xn2; xc3 = xn3;
    }

    // ---- cross-wave K-reduction (pairwise over LDS, XOR-swizzled float4 cols) ----
    auto dump = [&](int b) {
#pragma unroll
        for (int e4 = 0; e4 < 16; ++e4) {
            int col = (e4 ^ (lane & 15)) * 4;
            *(float4*)&redf[b][lane][col] =
                make_float4(acc[e4*4], acc[e4*4+1], acc[e4*4+2], acc[e4*4+3]);
        }
    };
    auto gather = [&](int b) {
#pragma unroll
        for (int e4 = 0; e4 < 16; ++e4) {
            int col = (e4 ^ (lane & 15)) * 4;
            float4 v = *(const float4*)&redf[b][lane][col];
            acc[e4*4]   += v.x;
            acc[e4*4+1] += v.y;
            acc[e4*4+2] += v.z;
            acc[e4*4+3] += v.w;
        }
    };

    if (wv >= 4) dump(wv - 4);
    __syncthreads();
    if (wv < 4) gather(wv);
    __syncthreads();
    if (wv == 2 || wv == 3) dump(wv - 2);
    __syncthreads();
    if (wv < 2) gather(wv);
    __syncthreads();
    if (wv == 1) dump(0);
    __syncthreads();

    // ---- epilogue: wave 0 holds full logits, one token per lane, all in regs ----
    if (wv == 0) {
        gather(0);

        // top-2, strict > keeps lower index on ties (matches lax.top_k)
        float v1 = acc[0]; int i1 = 0;
        float v2 = -INFINITY; int i2 = 0;
#pragma unroll
        for (int e = 1; e < E; ++e) {
            float v = acc[e];
            if (v > v1)      { v2 = v1; i2 = i1; v1 = v; i1 = e; }
            else if (v > v2) { v2 = v;  i2 = e; }
        }

        // in-place softmax over 64 experts (v1 is the max)
        float s = 0.f;
#pragma unroll
        for (int e = 0; e < E; ++e) { acc[e] = __expf(acc[e] - v1); s += acc[e]; }
        float inv = 1.f / s;

        // stage p and (p>0) per token into LDS for the per-expert transpose-reduce
#pragma unroll
        for (int e4 = 0; e4 < 16; ++e4) {
            int col = (e4 ^ (lane & 15)) * 4;
            float p0 = acc[e4*4]   * inv;
            float p1 = acc[e4*4+1] * inv;
            float p2 = acc[e4*4+2] * inv;
            float p3 = acc[e4*4+3] * inv;
            *(float4*)&redf[0][lane][col] = make_float4(p0, p1, p2, p3);
            *(float4*)&redf[1][lane][col] = make_float4(p0 > 0.f ? 1.f : 0.f,
                                                        p1 > 0.f ? 1.f : 0.f,
                                                        p2 > 0.f ? 1.f : 0.f,
                                                        p3 > 0.f ? 1.f : 0.f);
        }

        // gates / indices (coalesced float2 per lane)
        float t = __expf(v2 - v1);
        float d = 1.f / (1.f + t);
        *(float2*)&out[GATES_OFF + 2 * token] = make_float2(d, t * d);
        *(float2*)&out[IDX_OFF   + 2 * token] = make_float2((float)i1, (float)i2);
    }
    __syncthreads();

    // ---- per-expert partial sums: lane = expert, each wave covers 8 tokens ----
    {
        const int e = lane;
        float sp = 0.f, sc = 0.f;
#pragma unroll
        for (int t0 = 0; t0 < 8; ++t0) {
            int tt  = wv * 8 + t0;
            int idx = (((e >> 2) ^ (tt & 15)) << 2) + (e & 3);
            sp += redf[0][tt][idx];
            sc += redf[1][tt][idx];
        }
        atomicAdd(&accum[e],     sp);
        atomicAdd(&accum[E + e], sc);
    }
}

// ---------------- final loss kernel ----------------
__global__ void gate_final_kernel(const float* __restrict__ accum, float* __restrict__ out) {
    int lane = threadIdx.x;                  // 64 threads
    const float invT = 1.f / (float)T_TOK;
    float mean_p  = accum[lane] * invT;
    float routing = accum[E + lane] * invT;
    float term = mean_p * routing;
#pragma unroll
    for (int d = 32; d > 0; d >>= 1) term += __shfl_xor(term, d, 64);
    if (lane == 0) out[LOSS_OFF] = 64.f * term;
}

extern "C" void kernel_launch(void* const* d_in, const int* in_sizes, int n_in,
                              void* d_out, int out_size, void* d_ws, size_t ws_size,
                              hipStream_t stream) {
    const float* x = (const float*)d_in[0];   // (4,8192,2048) fp32
    const float* W = (const float*)d_in[1];   // (64,2048) fp32
    float* out   = (float*)d_out;
    float* accum = (float*)d_ws;              // 128 floats

    zero_accum_kernel<<<1, 128, 0, stream>>>(accum);
    gate_main_kernel<<<T_TOK / 64, 512, 0, stream>>>(x, W, out, accum);
    gate_final_kernel<<<1, 64, 0, stream>>>(accum, out);
}

// Round 2
// 673.494 us; speedup vs baseline: 1.6388x; 1.6388x over previous
//
#include <hip/hip_runtime.h>
#include <math.h>

#define H       2048
#define E       64
#define NCHUNK  16          // chunks of 128 floats across H; each wave owns 16 floats/chunk
#define T_TOK   32768
#define GATES_OFF   0
#define IDX_OFF     65536
#define LOSS_OFF    131072

// ---- zero the 128-float accumulator ----
__global__ void zero_accum_kernel(float* __restrict__ accum) {
    accum[threadIdx.x] = 0.f;    // 128 threads
}

// ---------------- main gating kernel ----------------
// lane = token (64 tokens/block), acc[64] = one logit per expert in VGPRs.
// 8 waves split H: wave w owns floats [c*128 + w*16, +16) of each token row
// -> each lane reads exactly one full 64B line per chunk (no LDS in main loop).
// W addresses are wave-uniform (one 64B line per load after coalescing).
// __launch_bounds__(512,4): VGPR budget 128 -- acc(64)+x(16)+W pipeline fits,
// no spills (round-1 at default heuristic: VGPR=76 + 27MB scratch traffic).
__global__ __launch_bounds__(512, 4) void gate_main_kernel(
        const float* __restrict__ x,         // (T, H) fp32
        const float* __restrict__ W,         // (E, H) fp32, row-major
        float* __restrict__ out,
        float* __restrict__ accum)           // [0:64) sum probs, [64:128) counts
{
    __shared__ float redf[4][64][64];        // 64 KB: K-reduction, then p/cnt staging

    const int tid   = threadIdx.x;
    const int lane  = tid & 63;
    const int wv    = tid >> 6;
    const int wvu   = __builtin_amdgcn_readfirstlane(wv);   // force SGPR-uniform
    const int token = blockIdx.x * 64 + lane;

    const float4* xrow = (const float4*)(x + (size_t)token * H) + wvu * 4;
    const float4* Wv   = (const float4*)W;   // [E][512] float4 view

    float acc[E];
#pragma unroll
    for (int e = 0; e < E; ++e) acc[e] = 0.f;

    for (int c = 0; c < NCHUNK; ++c) {
        // this wave's 64B slice of the chunk (one cache line per lane)
        const float4 xc0 = xrow[c * 32 + 0];
        const float4 xc1 = xrow[c * 32 + 1];
        const float4 xc2 = xrow[c * 32 + 2];
        const float4 xc3 = xrow[c * 32 + 3];

        const float4* wp = Wv + c * 32 + wvu * 4;
#pragma unroll
        for (int e = 0; e < E; ++e) {
            float4 w0 = wp[e * 512 + 0];
            float4 w1 = wp[e * 512 + 1];
            float4 w2 = wp[e * 512 + 2];
            float4 w3 = wp[e * 512 + 3];
            float a = acc[e];
            a = fmaf(xc0.x, w0.x, a);
            a = fmaf(xc0.y, w0.y, a);
            a = fmaf(xc0.z, w0.z, a);
            a = fmaf(xc0.w, w0.w, a);
            a = fmaf(xc1.x, w1.x, a);
            a = fmaf(xc1.y, w1.y, a);
            a = fmaf(xc1.z, w1.z, a);
            a = fmaf(xc1.w, w1.w, a);
            a = fmaf(xc2.x, w2.x, a);
            a = fmaf(xc2.y, w2.y, a);
            a = fmaf(xc2.z, w2.z, a);
            a = fmaf(xc2.w, w2.w, a);
            a = fmaf(xc3.x, w3.x, a);
            a = fmaf(xc3.y, w3.y, a);
            a = fmaf(xc3.z, w3.z, a);
            a = fmaf(xc3.w, w3.w, a);
            acc[e] = a;
        }
    }

    // ---- cross-wave K-reduction (pairwise over LDS, XOR-swizzled float4 cols) ----
    auto dump = [&](int b) {
#pragma unroll
        for (int e4 = 0; e4 < 16; ++e4) {
            int col = (e4 ^ (lane & 15)) * 4;
            *(float4*)&redf[b][lane][col] =
                make_float4(acc[e4*4], acc[e4*4+1], acc[e4*4+2], acc[e4*4+3]);
        }
    };
    auto gather = [&](int b) {
#pragma unroll
        for (int e4 = 0; e4 < 16; ++e4) {
            int col = (e4 ^ (lane & 15)) * 4;
            float4 v = *(const float4*)&redf[b][lane][col];
            acc[e4*4]   += v.x;
            acc[e4*4+1] += v.y;
            acc[e4*4+2] += v.z;
            acc[e4*4+3] += v.w;
        }
    };

    if (wv >= 4) dump(wv - 4);
    __syncthreads();
    if (wv < 4) gather(wv);
    __syncthreads();
    if (wv == 2 || wv == 3) dump(wv - 2);
    __syncthreads();
    if (wv < 2) gather(wv);
    __syncthreads();
    if (wv == 1) dump(0);
    __syncthreads();

    // ---- epilogue: wave 0 holds full logits, one token per lane, all in regs ----
    if (wv == 0) {
        gather(0);

        // top-2, strict > keeps lower index on ties (matches lax.top_k)
        float v1 = acc[0]; int i1 = 0;
        float v2 = -INFINITY; int i2 = 0;
#pragma unroll
        for (int e = 1; e < E; ++e) {
            float v = acc[e];
            if (v > v1)      { v2 = v1; i2 = i1; v1 = v; i1 = e; }
            else if (v > v2) { v2 = v;  i2 = e; }
        }

        // in-place softmax over 64 experts (v1 is the max)
        float s = 0.f;
#pragma unroll
        for (int e = 0; e < E; ++e) { acc[e] = __expf(acc[e] - v1); s += acc[e]; }
        float inv = 1.f / s;

        // stage p and (p>0) per token into LDS for the per-expert transpose-reduce
#pragma unroll
        for (int e4 = 0; e4 < 16; ++e4) {
            int col = (e4 ^ (lane & 15)) * 4;
            float p0 = acc[e4*4]   * inv;
            float p1 = acc[e4*4+1] * inv;
            float p2 = acc[e4*4+2] * inv;
            float p3 = acc[e4*4+3] * inv;
            *(float4*)&redf[0][lane][col] = make_float4(p0, p1, p2, p3);
            *(float4*)&redf[1][lane][col] = make_float4(p0 > 0.f ? 1.f : 0.f,
                                                        p1 > 0.f ? 1.f : 0.f,
                                                        p2 > 0.f ? 1.f : 0.f,
                                                        p3 > 0.f ? 1.f : 0.f);
        }

        // gates / indices (coalesced float2 per lane)
        float t = __expf(v2 - v1);
        float d = 1.f / (1.f + t);
        *(float2*)&out[GATES_OFF + 2 * token] = make_float2(d, t * d);
        *(float2*)&out[IDX_OFF   + 2 * token] = make_float2((float)i1, (float)i2);
    }
    __syncthreads();

    // ---- per-expert partial sums: lane = expert, each wave covers 8 tokens ----
    {
        const int e = lane;
        float sp = 0.f, sc = 0.f;
#pragma unroll
        for (int t0 = 0; t0 < 8; ++t0) {
            int tt  = wv * 8 + t0;
            int idx = (((e >> 2) ^ (tt & 15)) << 2) + (e & 3);
            sp += redf[0][tt][idx];
            sc += redf[1][tt][idx];
        }
        atomicAdd(&accum[e],     sp);
        atomicAdd(&accum[E + e], sc);
    }
}

// ---------------- final loss kernel ----------------
__global__ void gate_final_kernel(const float* __restrict__ accum, float* __restrict__ out) {
    int lane = threadIdx.x;                  // 64 threads
    const float invT = 1.f / (float)T_TOK;
    float mean_p  = accum[lane] * invT;
    float routing = accum[E + lane] * invT;
    float term = mean_p * routing;
#pragma unroll
    for (int d = 32; d > 0; d >>= 1) term += __shfl_xor(term, d, 64);
    if (lane == 0) out[LOSS_OFF] = 64.f * term;
}

extern "C" void kernel_launch(void* const* d_in, const int* in_sizes, int n_in,
                              void* d_out, int out_size, void* d_ws, size_t ws_size,
                              hipStream_t stream) {
    const float* x = (const float*)d_in[0];   // (4,8192,2048) fp32
    const float* W = (const float*)d_in[1];   // (64,2048) fp32
    float* out   = (float*)d_out;
    float* accum = (float*)d_ws;              // 128 floats

    zero_accum_kernel<<<1, 128, 0, stream>>>(accum);
    gate_main_kernel<<<T_TOK / 64, 512, 0, stream>>>(x, W, out, accum);
    gate_final_kernel<<<1, 64, 0, stream>>>(accum, out);
}